// Round 5
// baseline (99.914 us; speedup 1.0000x reference)
//
#include <hip/hip_runtime.h>

#define D    64
#define K    512
#define QTOT (8 * 16384)
#define THR  0.008f

typedef __attribute__((ext_vector_type(8))) short short8;   // 8 bf16 payloads (4 VGPRs)
typedef __attribute__((ext_vector_type(4))) short short4v;  // 4 bf16 payloads (8 B)
typedef __attribute__((ext_vector_type(4))) float f32x4;

__device__ __forceinline__ unsigned short f2bf(float f) {   // fp32 -> bf16 (RNE)
    unsigned u = __builtin_bit_cast(unsigned, f);
    u = u + 0x7FFFu + ((u >> 16) & 1u);
    return (unsigned short)(u >> 16);
}
__device__ __forceinline__ float bf2f(unsigned short h) {
    unsigned u = ((unsigned)h) << 16;
    return __builtin_bit_cast(float, u);
}

// ================= FAST path (uses d_ws) =================
// prep: esq + linear bf16 hi/lo split of the codebook, once per call.
__global__ __launch_bounds__(512) void prep_kernel(const float* __restrict__ cb,
        float* __restrict__ esq, unsigned short* __restrict__ ehi,
        unsigned short* __restrict__ elo) {
    const int tid = threadIdx.x;
    const float4* cbv4 = (const float4*)cb;
    for (int c = tid; c < (K * D) / 4; c += 512) {          // coalesced convert
        float4 v = cbv4[c];
        float vv[4] = {v.x, v.y, v.z, v.w};
        short4v hi, lo;
        #pragma unroll
        for (int j = 0; j < 4; ++j) {
            unsigned short hb = f2bf(vv[j]);
            hi[j] = (short)hb;
            lo[j] = (short)f2bf(vv[j] - bf2f(hb));
        }
        ((short4v*)ehi)[c] = hi;
        ((short4v*)elo)[c] = lo;
    }
    // esq: row per thread (tid==row), deterministic ascending fmaf chain
    const float4* rp = (const float4*)(cb + (size_t)tid * D);
    float s = 0.f;
    #pragma unroll
    for (int i = 0; i < 16; ++i) {
        float4 v = rp[i];
        s = fmaf(v.x, v.x, s); s = fmaf(v.y, v.y, s);
        s = fmaf(v.z, v.z, s); s = fmaf(v.w, v.w, s);
    }
    esq[tid] = s;
}

// main: 512 thr (8 waves) x 32 queries/wave; A-fragments from L1/L2-hot global;
// LDS = 2 KB only -> 2 blocks/CU, 4 waves/SIMD; builtin MFMA for scheduling.
__global__ __launch_bounds__(512, 4) void vq_fast(const float* __restrict__ x,
        const float* __restrict__ cb, const float* __restrict__ g_esq,
        const unsigned short* __restrict__ ehi, const unsigned short* __restrict__ elo,
        float* __restrict__ out) {

    __shared__ float s_esq[K];

    const int tid  = threadIdx.x;
    const int lane = tid & 63;
    const int qrow = lane & 15;                 // query col of C / code row of A
    const int kg   = lane >> 4;
    const int wv   = __builtin_amdgcn_readfirstlane(tid >> 6);
    const int qw   = blockIdx.x * 256 + wv * 32;   // wave's first query

    s_esq[tid] = g_esq[tid];                    // K == 512 == blockDim
    __syncthreads();

    // B-fragments: lane slot (kg, j) holds x[query][h*32 + kg*8 + j], hi/lo split.
    // A-slots use the same (kg, j) -> dim map, so pairing is k-order independent.
    short8 xh[2][2], xl[2][2];
    #pragma unroll
    for (int qt = 0; qt < 2; ++qt) {
        #pragma unroll
        for (int h = 0; h < 2; ++h) {
            const float* p = x + (size_t)(qw + qt * 16 + qrow) * D + h * 32 + kg * 8;
            float4 v0 = *(const float4*)p;
            float4 v1 = *(const float4*)(p + 4);
            float vv[8] = {v0.x, v0.y, v0.z, v0.w, v1.x, v1.y, v1.z, v1.w};
            short8 th, tl;
            #pragma unroll
            for (int j = 0; j < 8; ++j) {
                unsigned short hb = f2bf(vv[j]);
                th[j] = (short)hb;
                tl[j] = (short)f2bf(vv[j] - bf2f(hb));
            }
            xh[qt][h] = th;
            xl[qt][h] = tl;
        }
    }

    float m1[2], m2[2];
    int   i1[2];
    #pragma unroll
    for (int qt = 0; qt < 2; ++qt) { m1[qt] = 3.4e38f; m2[qt] = 3.4e38f; i1[qt] = 0; }

    for (int t = 0; t < 32; ++t) {
        const int row = t * 16 + qrow;          // A-operand code row
        const short8* hp = (const short8*)(ehi + (size_t)row * D);
        const short8* lp = (const short8*)(elo + (size_t)row * D);
        short8 eh0 = hp[kg], eh1 = hp[4 + kg];  // dims kg*8 and 32+kg*8
        short8 el0 = lp[kg], el1 = lp[4 + kg];
        f32x4 eq = *(const f32x4*)(s_esq + t * 16 + kg * 4);

        #pragma unroll
        for (int qt = 0; qt < 2; ++qt) {
            f32x4 acc = {0.f, 0.f, 0.f, 0.f};   // same accumulation order as round 4
            acc = __builtin_amdgcn_mfma_f32_16x16x32_bf16(eh0, xh[qt][0], acc, 0, 0, 0);
            acc = __builtin_amdgcn_mfma_f32_16x16x32_bf16(eh1, xh[qt][1], acc, 0, 0, 0);
            acc = __builtin_amdgcn_mfma_f32_16x16x32_bf16(eh0, xl[qt][0], acc, 0, 0, 0);
            acc = __builtin_amdgcn_mfma_f32_16x16x32_bf16(eh1, xl[qt][1], acc, 0, 0, 0);
            acc = __builtin_amdgcn_mfma_f32_16x16x32_bf16(el0, xh[qt][0], acc, 0, 0, 0);
            acc = __builtin_amdgcn_mfma_f32_16x16x32_bf16(el1, xh[qt][1], acc, 0, 0, 0);
            #pragma unroll
            for (int r = 0; r < 4; ++r) {
                float dd = fmaf(-2.f, acc[r], eq[r]);   // d2 proxy (x_sq const, sqrt monotone)
                int   kc = t * 16 + kg * 4 + r;
                bool  lt = dd < m1[qt];
                m2[qt] = lt ? m1[qt] : fminf(m2[qt], dd);
                m1[qt] = lt ? dd : m1[qt];
                i1[qt] = lt ? kc : i1[qt];
            }
        }
    }

    // combine (m1,i1,m2) across the 4 k-groups holding each query
    #pragma unroll
    for (int qt = 0; qt < 2; ++qt) {
        #pragma unroll
        for (int off = 16; off <= 32; off <<= 1) {
            float om1 = __shfl_xor(m1[qt], off, 64);
            float om2 = __shfl_xor(m2[qt], off, 64);
            int   oi  = __shfl_xor(i1[qt], off, 64);
            bool  lt  = om1 < m1[qt];
            float loser = lt ? m1[qt] : om1;
            m2[qt] = fminf(fminf(m2[qt], om2), loser);
            m1[qt] = lt ? om1 : m1[qt];
            i1[qt] = lt ? oi  : i1[qt];
        }
    }

    // exact fp32 rescan when top-2 gap <= THR >= 2*(bf16x3 bound): fp32 argmin
    // guaranteed; approx ties (gap 0) also land here -> first-index restored.
    #pragma unroll
    for (int qt = 0; qt < 2; ++qt) {
        bool flag = (m2[qt] - m1[qt]) <= THR;
        unsigned long long mask = __ballot(flag && (lane < 16));
        while (mask) {
            int ql = __ffsll(mask) - 1;
            mask &= mask - 1;
            int qf = qw + qt * 16 + ql;                 // wave-uniform
            const float* xq = x + (size_t)qf * D;
            float bb = 3.4e38f;
            int   bq = 0;
            #pragma unroll 1
            for (int c0 = 0; c0 < 8; ++c0) {
                int kc = lane * 8 + c0;
                const float4* ep = (const float4*)(cb + (size_t)kc * D);
                float a = 0.f;
                #pragma unroll
                for (int i = 0; i < 16; ++i) {
                    float4 e = ep[i];
                    a = fmaf(xq[4 * i + 0], e.x, a);
                    a = fmaf(xq[4 * i + 1], e.y, a);
                    a = fmaf(xq[4 * i + 2], e.z, a);
                    a = fmaf(xq[4 * i + 3], e.w, a);
                }
                float dd = fmaf(-2.f, a, s_esq[kc]);
                if (dd < bb) { bb = dd; bq = kc; }      // ascending kc: first index wins
            }
            #pragma unroll
            for (int off = 1; off < 64; off <<= 1) {    // min-reduce, first-index tie-break
                float ob = __shfl_xor(bb, off, 64);
                int   oq = __shfl_xor(bq, off, 64);
                if (ob < bb || (ob == bb && oq < bq)) { bb = ob; bq = oq; }
            }
            if (qrow == ql) i1[qt] = bq;
        }
    }

    // emit: out[q] = cb[i1]; lane (qrow,kg) writes 64 B of query qrow's row
    #pragma unroll
    for (int qt = 0; qt < 2; ++qt) {
        size_t q = (size_t)(qw + qt * 16 + qrow);
        const float4* src = (const float4*)(cb + (size_t)i1[qt] * D) + kg * 4;
        float4*       dst = (float4*)(out + q * D) + kg * 4;
        #pragma unroll
        for (int s = 0; s < 4; ++s) dst[s] = src[s];
    }
}

// ================= SAFE fallback: round-4 kernel verbatim (proven) =================
__global__ __launch_bounds__(512) void vq_mfma(
        const float* __restrict__ x, const float* __restrict__ cb,
        float* __restrict__ out) {

    __shared__ unsigned short s_e[2][K * D];
    __shared__ float s_esq[K];

    const int tid  = threadIdx.x;
    const int lane = tid & 63;
    const int qrow = lane & 15;
    const int kg   = lane >> 4;
    const int wv   = __builtin_amdgcn_readfirstlane(tid >> 6);
    const int qw   = blockIdx.x * 512 + wv * 64;

    const float4* cbv4 = (const float4*)cb;
    for (int c = tid; c < (K * D) / 4; c += 512) {
        float4 v = cbv4[c];
        float vv[4] = {v.x, v.y, v.z, v.w};
        short4v hi, lo;
        #pragma unroll
        for (int j = 0; j < 4; ++j) {
            unsigned short hb = f2bf(vv[j]);
            hi[j] = (short)hb;
            lo[j] = (short)f2bf(vv[j] - bf2f(hb));
        }
        int byteoff = c * 8;
        int row     = byteoff >> 7;
        int addr    = byteoff ^ ((row & 7) << 4);
        *(short4v*)((char*)s_e[0] + addr) = hi;
        *(short4v*)((char*)s_e[1] + addr) = lo;
    }
    {
        float s = 0.f;
        #pragma unroll
        for (int d = 0; d < D; ++d) {
            float v = cb[tid * D + d];
            s = fmaf(v, v, s);
        }
        s_esq[tid] = s;
    }
    __syncthreads();

    short8 xh[4][2], xl[4][2];
    #pragma unroll
    for (int qt = 0; qt < 4; ++qt) {
        #pragma unroll
        for (int h = 0; h < 2; ++h) {
            const float* p = x + (size_t)(qw + qt * 16 + qrow) * D + h * 32 + kg * 8;
            float4 v0 = *(const float4*)p;
            float4 v1 = *(const float4*)(p + 4);
            float vv[8] = {v0.x, v0.y, v0.z, v0.w, v1.x, v1.y, v1.z, v1.w};
            short8 th, tl;
            #pragma unroll
            for (int j = 0; j < 8; ++j) {
                unsigned short hb = f2bf(vv[j]);
                th[j] = (short)hb;
                tl[j] = (short)f2bf(vv[j] - bf2f(hb));
            }
            xh[qt][h] = th;
            xl[qt][h] = tl;
        }
    }

    float m1[4], m2[4];
    int   i1[4];
    #pragma unroll
    for (int qt = 0; qt < 4; ++qt) { m1[qt] = 3.4e38f; m2[qt] = 3.4e38f; i1[qt] = 0; }

    const f32x4 zacc = {0.f, 0.f, 0.f, 0.f};

    for (int t = 0; t < 32; ++t) {
        const int row  = t * 16 + qrow;
        const int swz  = (row & 7) << 4;
        const int off0 = row * 128 + kg * 16;
        short8 eh0 = *(const short8*)((const char*)s_e[0] + ((off0     ) ^ swz));
        short8 eh1 = *(const short8*)((const char*)s_e[0] + ((off0 + 64) ^ swz));
        short8 el0 = *(const short8*)((const char*)s_e[1] + ((off0     ) ^ swz));
        short8 el1 = *(const short8*)((const char*)s_e[1] + ((off0 + 64) ^ swz));
        f32x4 eq = *(const f32x4*)(s_esq + t * 16 + kg * 4);

        #pragma unroll
        for (int qt = 0; qt < 4; ++qt) {
            f32x4 acc;
            asm volatile(
                "s_nop 3\n\t"
                "v_mfma_f32_16x16x32_bf16 %0, %1, %5, %9\n\t"
                "v_mfma_f32_16x16x32_bf16 %0, %2, %6, %0\n\t"
                "v_mfma_f32_16x16x32_bf16 %0, %1, %7, %0\n\t"
                "v_mfma_f32_16x16x32_bf16 %0, %2, %8, %0\n\t"
                "v_mfma_f32_16x16x32_bf16 %0, %3, %5, %0\n\t"
                "v_mfma_f32_16x16x32_bf16 %0, %4, %6, %0\n\t"
                "s_nop 7\n\t"
                "s_nop 7"
                : "=&v"(acc)
                : "v"(eh0), "v"(eh1), "v"(el0), "v"(el1),
                  "v"(xh[qt][0]), "v"(xh[qt][1]), "v"(xl[qt][0]), "v"(xl[qt][1]),
                  "v"(zacc));
            #pragma unroll
            for (int r = 0; r < 4; ++r) {
                float dd = fmaf(-2.f, acc[r], eq[r]);
                int   kc = t * 16 + kg * 4 + r;
                bool  lt = dd < m1[qt];
                m2[qt] = lt ? m1[qt] : fminf(m2[qt], dd);
                m1[qt] = lt ? dd : m1[qt];
                i1[qt] = lt ? kc : i1[qt];
            }
        }
    }

    #pragma unroll
    for (int qt = 0; qt < 4; ++qt) {
        #pragma unroll
        for (int off = 16; off <= 32; off <<= 1) {
            float om1 = __shfl_xor(m1[qt], off, 64);
            float om2 = __shfl_xor(m2[qt], off, 64);
            int   oi  = __shfl_xor(i1[qt], off, 64);
            bool  lt  = om1 < m1[qt];
            float loser = lt ? m1[qt] : om1;
            m2[qt] = fminf(fminf(m2[qt], om2), loser);
            m1[qt] = lt ? om1 : m1[qt];
            i1[qt] = lt ? oi  : i1[qt];
        }
    }

    #pragma unroll
    for (int qt = 0; qt < 4; ++qt) {
        bool flag = (m2[qt] - m1[qt]) <= THR;
        unsigned long long mask = __ballot(flag && (lane < 16));
        while (mask) {
            int ql = __ffsll(mask) - 1;
            mask &= mask - 1;
            int qf = qw + qt * 16 + ql;
            const float* xq = x + (size_t)qf * D;
            float bb = 3.4e38f;
            int   bq = 0;
            #pragma unroll 1
            for (int c0 = 0; c0 < 8; ++c0) {
                int kc = lane * 8 + c0;
                const float4* ep = (const float4*)(cb + (size_t)kc * D);
                float a = 0.f;
                #pragma unroll
                for (int i = 0; i < 16; ++i) {
                    float4 e = ep[i];
                    a = fmaf(xq[4 * i + 0], e.x, a);
                    a = fmaf(xq[4 * i + 1], e.y, a);
                    a = fmaf(xq[4 * i + 2], e.z, a);
                    a = fmaf(xq[4 * i + 3], e.w, a);
                }
                float dd = fmaf(-2.f, a, s_esq[kc]);
                if (dd < bb) { bb = dd; bq = kc; }
            }
            #pragma unroll
            for (int off = 1; off < 64; off <<= 1) {
                float ob = __shfl_xor(bb, off, 64);
                int   oq = __shfl_xor(bq, off, 64);
                if (ob < bb || (ob == bb && oq < bq)) { bb = ob; bq = oq; }
            }
            if (qrow == ql) i1[qt] = bq;
        }
    }

    #pragma unroll
    for (int qt = 0; qt < 4; ++qt) {
        size_t q = (size_t)(qw + qt * 16 + qrow);
        const float4* src = (const float4*)(cb + (size_t)i1[qt] * D) + kg * 4;
        float4*       dst = (float4*)(out + q * D) + kg * 4;
        #pragma unroll
        for (int s = 0; s < 4; ++s) dst[s] = src[s];
    }
}

extern "C" void kernel_launch(void* const* d_in, const int* in_sizes, int n_in,
                              void* d_out, int out_size, void* d_ws, size_t ws_size,
                              hipStream_t stream) {
    const float* x   = (const float*)d_in[0];   // [8,16384,64]
    const float* cb  = (const float*)d_in[1];   // [512,64]
    float*       out = (float*)d_out;           // [8,16384,1,64]

    const size_t need = 2048 + (size_t)K * D * 2 * 2;   // esq + ehi + elo = 133120 B
    if (ws_size >= need) {
        float*          esq = (float*)d_ws;
        unsigned short* ehi = (unsigned short*)((char*)d_ws + 2048);
        unsigned short* elo = (unsigned short*)((char*)d_ws + 2048 + K * D * 2);
        prep_kernel<<<1, 512, 0, stream>>>(cb, esq, ehi, elo);
        vq_fast<<<QTOT / 256, 512, 0, stream>>>(x, cb, esq, ehi, elo, out);
    } else {
        vq_mfma<<<QTOT / 512, 512, 0, stream>>>(x, cb, out);
    }
}

// Round 6
// 65.065 us; speedup vs baseline: 1.5356x; 1.5356x over previous
//
#include <hip/hip_runtime.h>

#define D    64
#define K    512
#define QTOT (8 * 16384)
#define THR  0.008f

typedef __attribute__((ext_vector_type(8))) short short8;   // 8 bf16 payloads (4 VGPRs)
typedef __attribute__((ext_vector_type(4))) short short4v;  // 4 bf16 payloads (8 B)
typedef __attribute__((ext_vector_type(4))) float f32x4;

__device__ __forceinline__ unsigned short f2bf(float f) {   // fp32 -> bf16 (RNE)
    unsigned u = __builtin_bit_cast(unsigned, f);
    u = u + 0x7FFFu + ((u >> 16) & 1u);
    return (unsigned short)(u >> 16);
}
__device__ __forceinline__ float bf2f(unsigned short h) {
    unsigned u = ((unsigned)h) << 16;
    return __builtin_bit_cast(float, u);
}

// ---- prep (proven in round 5): esq + linear bf16 hi/lo split -> d_ws ----
__global__ __launch_bounds__(512) void prep_kernel(const float* __restrict__ cb,
        float* __restrict__ esq, unsigned short* __restrict__ ehi,
        unsigned short* __restrict__ elo) {
    const int tid = threadIdx.x;
    const float4* cbv4 = (const float4*)cb;
    for (int c = tid; c < (K * D) / 4; c += 512) {
        float4 v = cbv4[c];
        float vv[4] = {v.x, v.y, v.z, v.w};
        short4v hi, lo;
        #pragma unroll
        for (int j = 0; j < 4; ++j) {
            unsigned short hb = f2bf(vv[j]);
            hi[j] = (short)hb;
            lo[j] = (short)f2bf(vv[j] - bf2f(hb));
        }
        ((short4v*)ehi)[c] = hi;
        ((short4v*)elo)[c] = lo;
    }
    const float4* rp = (const float4*)(cb + (size_t)tid * D);
    float s = 0.f;
    #pragma unroll
    for (int i = 0; i < 16; ++i) {
        float4 v = rp[i];
        s = fmaf(v.x, v.x, s); s = fmaf(v.y, v.y, s);
        s = fmaf(v.z, v.z, s); s = fmaf(v.w, v.w, s);
    }
    esq[tid] = s;
}

// ---- main: round-4 LDS structure, builtin MFMAs, 2 independent acc chains ----
__global__ __launch_bounds__(512) void vq_mfma2(
        const float* __restrict__ x, const float* __restrict__ cb,
        const float* __restrict__ g_esq, const unsigned short* __restrict__ ehi,
        const unsigned short* __restrict__ elo, float* __restrict__ out) {

    __shared__ unsigned short s_e[2][K * D];   // hi/lo split codebook, XOR-swizzled
    __shared__ float s_esq[K];

    const int tid  = threadIdx.x;
    const int lane = tid & 63;
    const int qrow = lane & 15;                 // query col of C / code row of A
    const int kg   = lane >> 4;
    const int wv   = __builtin_amdgcn_readfirstlane(tid >> 6);
    const int qw   = blockIdx.x * 512 + wv * 64;   // wave's first query (qt=4 x 16)

    // stage pre-split codebook into swizzled LDS (8 iter/thread, no convert ALU)
    for (int c = tid; c < (K * D) / 8; c += 512) {
        short8 hv = ((const short8*)ehi)[c];
        short8 lv = ((const short8*)elo)[c];
        int byteoff = c * 16;
        int row     = byteoff >> 7;             // 128 B per code row
        int addr    = byteoff ^ ((row & 7) << 4);
        *(short8*)((char*)s_e[0] + addr) = hv;
        *(short8*)((char*)s_e[1] + addr) = lv;
    }
    s_esq[tid] = g_esq[tid];                    // K == 512 == blockDim
    __syncthreads();

    // B-fragments: lane slot (kg, j) holds x[query][h*32 + kg*8 + j], hi/lo split.
    // A-slots use the same (kg, j) -> dim map, so pairing is k-order independent.
    short8 xh[4][2], xl[4][2];
    #pragma unroll
    for (int qt = 0; qt < 4; ++qt) {
        #pragma unroll
        for (int h = 0; h < 2; ++h) {
            const float* p = x + (size_t)(qw + qt * 16 + qrow) * D + h * 32 + kg * 8;
            float4 v0 = *(const float4*)p;
            float4 v1 = *(const float4*)(p + 4);
            float vv[8] = {v0.x, v0.y, v0.z, v0.w, v1.x, v1.y, v1.z, v1.w};
            short8 th, tl;
            #pragma unroll
            for (int j = 0; j < 8; ++j) {
                unsigned short hb = f2bf(vv[j]);
                th[j] = (short)hb;
                tl[j] = (short)f2bf(vv[j] - bf2f(hb));
            }
            xh[qt][h] = th;
            xl[qt][h] = tl;
        }
    }

    float m1[4], m2[4];
    int   i1[4];
    #pragma unroll
    for (int qt = 0; qt < 4; ++qt) { m1[qt] = 3.4e38f; m2[qt] = 3.4e38f; i1[qt] = 0; }

    for (int t = 0; t < 32; ++t) {
        const int row  = t * 16 + qrow;         // A-operand code row
        const int swz  = (row & 7) << 4;
        const int off0 = row * 128 + kg * 16;
        short8 eh0 = *(const short8*)((const char*)s_e[0] + ((off0     ) ^ swz));
        short8 eh1 = *(const short8*)((const char*)s_e[0] + ((off0 + 64) ^ swz));
        short8 el0 = *(const short8*)((const char*)s_e[1] + ((off0     ) ^ swz));
        short8 el1 = *(const short8*)((const char*)s_e[1] + ((off0 + 64) ^ swz));
        f32x4 eq = *(const f32x4*)(s_esq + t * 16 + kg * 4);

        #pragma unroll
        for (int qt = 0; qt < 4; ++qt) {
            // two INDEPENDENT chains (2-deep + 4-deep) -> 8 chains in flight
            // across qt; compiler interleaves MFMAs + min-track freely.
            f32x4 a0 = {0.f, 0.f, 0.f, 0.f};
            f32x4 a1 = {0.f, 0.f, 0.f, 0.f};
            a0 = __builtin_amdgcn_mfma_f32_16x16x32_bf16(eh0, xh[qt][0], a0, 0, 0, 0);
            a0 = __builtin_amdgcn_mfma_f32_16x16x32_bf16(eh1, xh[qt][1], a0, 0, 0, 0);
            a1 = __builtin_amdgcn_mfma_f32_16x16x32_bf16(eh0, xl[qt][0], a1, 0, 0, 0);
            a1 = __builtin_amdgcn_mfma_f32_16x16x32_bf16(eh1, xl[qt][1], a1, 0, 0, 0);
            a1 = __builtin_amdgcn_mfma_f32_16x16x32_bf16(el0, xh[qt][0], a1, 0, 0, 0);
            a1 = __builtin_amdgcn_mfma_f32_16x16x32_bf16(el1, xh[qt][1], a1, 0, 0, 0);
            #pragma unroll
            for (int r = 0; r < 4; ++r) {
                float dd = fmaf(-2.f, a0[r] + a1[r], eq[r]);  // d2 proxy
                int   kc = (t * 16 + r) | (kg * 4);           // disjoint bits -> 1 op
                bool  lt = dd < m1[qt];
                m2[qt] = lt ? m1[qt] : fminf(m2[qt], dd);
                m1[qt] = lt ? dd : m1[qt];
                i1[qt] = lt ? kc : i1[qt];
            }
        }
    }

    // combine (m1,i1,m2) across the 4 k-groups holding each query
    #pragma unroll
    for (int qt = 0; qt < 4; ++qt) {
        #pragma unroll
        for (int off = 16; off <= 32; off <<= 1) {
            float om1 = __shfl_xor(m1[qt], off, 64);
            float om2 = __shfl_xor(m2[qt], off, 64);
            int   oi  = __shfl_xor(i1[qt], off, 64);
            bool  lt  = om1 < m1[qt];
            float loser = lt ? m1[qt] : om1;
            m2[qt] = fminf(fminf(m2[qt], om2), loser);
            m1[qt] = lt ? om1 : m1[qt];
            i1[qt] = lt ? oi  : i1[qt];
        }
    }

    // exact fp32 rescan when top-2 gap <= THR >= 2*(bf16x3 bound): fp32 argmin
    // guaranteed; approx ties (gap 0) also land here -> first-index restored.
    #pragma unroll
    for (int qt = 0; qt < 4; ++qt) {
        bool flag = (m2[qt] - m1[qt]) <= THR;
        unsigned long long mask = __ballot(flag && (lane < 16));
        while (mask) {
            int ql = __ffsll(mask) - 1;
            mask &= mask - 1;
            int qf = qw + qt * 16 + ql;                 // wave-uniform
            const float* xq = x + (size_t)qf * D;
            float bb = 3.4e38f;
            int   bq = 0;
            #pragma unroll 1
            for (int c0 = 0; c0 < 8; ++c0) {
                int kc = lane * 8 + c0;
                const float4* ep = (const float4*)(cb + (size_t)kc * D);
                float a = 0.f;
                #pragma unroll
                for (int i = 0; i < 16; ++i) {
                    float4 e = ep[i];
                    a = fmaf(xq[4 * i + 0], e.x, a);
                    a = fmaf(xq[4 * i + 1], e.y, a);
                    a = fmaf(xq[4 * i + 2], e.z, a);
                    a = fmaf(xq[4 * i + 3], e.w, a);
                }
                float dd = fmaf(-2.f, a, s_esq[kc]);
                if (dd < bb) { bb = dd; bq = kc; }      // ascending kc: first index wins
            }
            #pragma unroll
            for (int off = 1; off < 64; off <<= 1) {    // min-reduce, first-index tie-break
                float ob = __shfl_xor(bb, off, 64);
                int   oq = __shfl_xor(bq, off, 64);
                if (ob < bb || (ob == bb && oq < bq)) { bb = ob; bq = oq; }
            }
            if (qrow == ql) i1[qt] = bq;
        }
    }

    // emit: out[q] = cb[i1]; lane (qrow,kg) writes 64 B of query qrow's row
    #pragma unroll
    for (int qt = 0; qt < 4; ++qt) {
        size_t q = (size_t)(qw + qt * 16 + qrow);
        const float4* src = (const float4*)(cb + (size_t)i1[qt] * D) + kg * 4;
        float4*       dst = (float4*)(out + q * D) + kg * 4;
        #pragma unroll
        for (int s = 0; s < 4; ++s) dst[s] = src[s];
    }
}

// ================= SAFE fallback: round-4 kernel verbatim (proven) =================
__global__ __launch_bounds__(512) void vq_mfma(
        const float* __restrict__ x, const float* __restrict__ cb,
        float* __restrict__ out) {

    __shared__ unsigned short s_e[2][K * D];
    __shared__ float s_esq[K];

    const int tid  = threadIdx.x;
    const int lane = tid & 63;
    const int qrow = lane & 15;
    const int kg   = lane >> 4;
    const int wv   = __builtin_amdgcn_readfirstlane(tid >> 6);
    const int qw   = blockIdx.x * 512 + wv * 64;

    const float4* cbv4 = (const float4*)cb;
    for (int c = tid; c < (K * D) / 4; c += 512) {
        float4 v = cbv4[c];
        float vv[4] = {v.x, v.y, v.z, v.w};
        short4v hi, lo;
        #pragma unroll
        for (int j = 0; j < 4; ++j) {
            unsigned short hb = f2bf(vv[j]);
            hi[j] = (short)hb;
            lo[j] = (short)f2bf(vv[j] - bf2f(hb));
        }
        int byteoff = c * 8;
        int row     = byteoff >> 7;
        int addr    = byteoff ^ ((row & 7) << 4);
        *(short4v*)((char*)s_e[0] + addr) = hi;
        *(short4v*)((char*)s_e[1] + addr) = lo;
    }
    {
        float s = 0.f;
        #pragma unroll
        for (int d = 0; d < D; ++d) {
            float v = cb[tid * D + d];
            s = fmaf(v, v, s);
        }
        s_esq[tid] = s;
    }
    __syncthreads();

    short8 xh[4][2], xl[4][2];
    #pragma unroll
    for (int qt = 0; qt < 4; ++qt) {
        #pragma unroll
        for (int h = 0; h < 2; ++h) {
            const float* p = x + (size_t)(qw + qt * 16 + qrow) * D + h * 32 + kg * 8;
            float4 v0 = *(const float4*)p;
            float4 v1 = *(const float4*)(p + 4);
            float vv[8] = {v0.x, v0.y, v0.z, v0.w, v1.x, v1.y, v1.z, v1.w};
            short8 th, tl;
            #pragma unroll
            for (int j = 0; j < 8; ++j) {
                unsigned short hb = f2bf(vv[j]);
                th[j] = (short)hb;
                tl[j] = (short)f2bf(vv[j] - bf2f(hb));
            }
            xh[qt][h] = th;
            xl[qt][h] = tl;
        }
    }

    float m1[4], m2[4];
    int   i1[4];
    #pragma unroll
    for (int qt = 0; qt < 4; ++qt) { m1[qt] = 3.4e38f; m2[qt] = 3.4e38f; i1[qt] = 0; }

    const f32x4 zacc = {0.f, 0.f, 0.f, 0.f};

    for (int t = 0; t < 32; ++t) {
        const int row  = t * 16 + qrow;
        const int swz  = (row & 7) << 4;
        const int off0 = row * 128 + kg * 16;
        short8 eh0 = *(const short8*)((const char*)s_e[0] + ((off0     ) ^ swz));
        short8 eh1 = *(const short8*)((const char*)s_e[0] + ((off0 + 64) ^ swz));
        short8 el0 = *(const short8*)((const char*)s_e[1] + ((off0     ) ^ swz));
        short8 el1 = *(const short8*)((const char*)s_e[1] + ((off0 + 64) ^ swz));
        f32x4 eq = *(const f32x4*)(s_esq + t * 16 + kg * 4);

        #pragma unroll
        for (int qt = 0; qt < 4; ++qt) {
            f32x4 acc;
            asm volatile(
                "s_nop 3\n\t"
                "v_mfma_f32_16x16x32_bf16 %0, %1, %5, %9\n\t"
                "v_mfma_f32_16x16x32_bf16 %0, %2, %6, %0\n\t"
                "v_mfma_f32_16x16x32_bf16 %0, %1, %7, %0\n\t"
                "v_mfma_f32_16x16x32_bf16 %0, %2, %8, %0\n\t"
                "v_mfma_f32_16x16x32_bf16 %0, %3, %5, %0\n\t"
                "v_mfma_f32_16x16x32_bf16 %0, %4, %6, %0\n\t"
                "s_nop 7\n\t"
                "s_nop 7"
                : "=&v"(acc)
                : "v"(eh0), "v"(eh1), "v"(el0), "v"(el1),
                  "v"(xh[qt][0]), "v"(xh[qt][1]), "v"(xl[qt][0]), "v"(xl[qt][1]),
                  "v"(zacc));
            #pragma unroll
            for (int r = 0; r < 4; ++r) {
                float dd = fmaf(-2.f, acc[r], eq[r]);
                int   kc = t * 16 + kg * 4 + r;
                bool  lt = dd < m1[qt];
                m2[qt] = lt ? m1[qt] : fminf(m2[qt], dd);
                m1[qt] = lt ? dd : m1[qt];
                i1[qt] = lt ? kc : i1[qt];
            }
        }
    }

    #pragma unroll
    for (int qt = 0; qt < 4; ++qt) {
        #pragma unroll
        for (int off = 16; off <= 32; off <<= 1) {
            float om1 = __shfl_xor(m1[qt], off, 64);
            float om2 = __shfl_xor(m2[qt], off, 64);
            int   oi  = __shfl_xor(i1[qt], off, 64);
            bool  lt  = om1 < m1[qt];
            float loser = lt ? m1[qt] : om1;
            m2[qt] = fminf(fminf(m2[qt], om2), loser);
            m1[qt] = lt ? om1 : m1[qt];
            i1[qt] = lt ? oi  : i1[qt];
        }
    }

    #pragma unroll
    for (int qt = 0; qt < 4; ++qt) {
        bool flag = (m2[qt] - m1[qt]) <= THR;
        unsigned long long mask = __ballot(flag && (lane < 16));
        while (mask) {
            int ql = __ffsll(mask) - 1;
            mask &= mask - 1;
            int qf = qw + qt * 16 + ql;
            const float* xq = x + (size_t)qf * D;
            float bb = 3.4e38f;
            int   bq = 0;
            #pragma unroll 1
            for (int c0 = 0; c0 < 8; ++c0) {
                int kc = lane * 8 + c0;
                const float4* ep = (const float4*)(cb + (size_t)kc * D);
                float a = 0.f;
                #pragma unroll
                for (int i = 0; i < 16; ++i) {
                    float4 e = ep[i];
                    a = fmaf(xq[4 * i + 0], e.x, a);
                    a = fmaf(xq[4 * i + 1], e.y, a);
                    a = fmaf(xq[4 * i + 2], e.z, a);
                    a = fmaf(xq[4 * i + 3], e.w, a);
                }
                float dd = fmaf(-2.f, a, s_esq[kc]);
                if (dd < bb) { bb = dd; bq = kc; }
            }
            #pragma unroll
            for (int off = 1; off < 64; off <<= 1) {
                float ob = __shfl_xor(bb, off, 64);
                int   oq = __shfl_xor(bq, off, 64);
                if (ob < bb || (ob == bb && oq < bq)) { bb = ob; bq = oq; }
            }
            if (qrow == ql) i1[qt] = bq;
        }
    }

    #pragma unroll
    for (int qt = 0; qt < 4; ++qt) {
        size_t q = (size_t)(qw + qt * 16 + qrow);
        const float4* src = (const float4*)(cb + (size_t)i1[qt] * D) + kg * 4;
        float4*       dst = (float4*)(out + q * D) + kg * 4;
        #pragma unroll
        for (int s = 0; s < 4; ++s) dst[s] = src[s];
    }
}

extern "C" void kernel_launch(void* const* d_in, const int* in_sizes, int n_in,
                              void* d_out, int out_size, void* d_ws, size_t ws_size,
                              hipStream_t stream) {
    const float* x   = (const float*)d_in[0];   // [8,16384,64]
    const float* cb  = (const float*)d_in[1];   // [512,64]
    float*       out = (float*)d_out;           // [8,16384,1,64]

    const size_t need = 2048 + (size_t)K * D * 2 * 2;   // esq + ehi + elo = 133120 B
    if (ws_size >= need) {
        float*          esq = (float*)d_ws;
        unsigned short* ehi = (unsigned short*)((char*)d_ws + 2048);
        unsigned short* elo = (unsigned short*)((char*)d_ws + 2048 + K * D * 2);
        prep_kernel<<<1, 512, 0, stream>>>(cb, esq, ehi, elo);
        vq_mfma2<<<QTOT / 512, 512, 0, stream>>>(x, cb, esq, ehi, elo, out);
    } else {
        vq_mfma<<<QTOT / 512, 512, 0, stream>>>(x, cb, out);
    }
}

// Round 7
// 58.472 us; speedup vs baseline: 1.7087x; 1.1128x over previous
//
#include <hip/hip_runtime.h>

#define D    64
#define K    512
#define QTOT (8 * 16384)
#define THR  0.008f

typedef __attribute__((ext_vector_type(8))) short short8;   // 8 bf16 payloads (4 VGPRs)
typedef __attribute__((ext_vector_type(4))) short short4v;  // 4 bf16 payloads (8 B)
typedef __attribute__((ext_vector_type(4))) float f32x4;

__device__ __forceinline__ unsigned short f2bf(float f) {   // fp32 -> bf16 (RNE)
    unsigned u = __builtin_bit_cast(unsigned, f);
    u = u + 0x7FFFu + ((u >> 16) & 1u);
    return (unsigned short)(u >> 16);
}
__device__ __forceinline__ float bf2f(unsigned short h) {
    unsigned u = ((unsigned)h) << 16;
    return __builtin_bit_cast(float, u);
}

// ---- prep (proven): esq + linear bf16 hi/lo split -> d_ws ----
__global__ __launch_bounds__(512) void prep_kernel(const float* __restrict__ cb,
        float* __restrict__ esq, unsigned short* __restrict__ ehi,
        unsigned short* __restrict__ elo) {
    const int tid = threadIdx.x;
    const float4* cbv4 = (const float4*)cb;
    for (int c = tid; c < (K * D) / 4; c += 512) {
        float4 v = cbv4[c];
        float vv[4] = {v.x, v.y, v.z, v.w};
        short4v hi, lo;
        #pragma unroll
        for (int j = 0; j < 4; ++j) {
            unsigned short hb = f2bf(vv[j]);
            hi[j] = (short)hb;
            lo[j] = (short)f2bf(vv[j] - bf2f(hb));
        }
        ((short4v*)ehi)[c] = hi;
        ((short4v*)elo)[c] = lo;
    }
    const float4* rp = (const float4*)(cb + (size_t)tid * D);
    float s = 0.f;
    #pragma unroll
    for (int i = 0; i < 16; ++i) {
        float4 v = rp[i];
        s = fmaf(v.x, v.x, s); s = fmaf(v.y, v.y, s);
        s = fmaf(v.z, v.z, s); s = fmaf(v.w, v.w, s);
    }
    esq[tid] = s;
}

// ---- main: 1024 thr = 16 waves (4/SIMD), qt=2, LDS-resident split codebook ----
__global__ __launch_bounds__(1024) void vq_mfma3(
        const float* __restrict__ x, const float* __restrict__ cb,
        const float* __restrict__ g_esq, const unsigned short* __restrict__ ehi,
        const unsigned short* __restrict__ elo, float* __restrict__ out) {

    __shared__ unsigned short s_e[2][K * D];   // hi/lo split codebook, XOR-swizzled
    __shared__ float s_esq[K];

    const int tid  = threadIdx.x;
    const int lane = tid & 63;
    const int qrow = lane & 15;                 // query col of C / code row of A
    const int kg   = lane >> 4;
    const int wv   = __builtin_amdgcn_readfirstlane(tid >> 6);   // 0..15
    const int qw   = blockIdx.x * 512 + wv * 32;   // wave's first query (qt=2 x 16)

    // stage pre-split codebook into swizzled LDS (4 iters/thread)
    for (int c = tid; c < (K * D) / 8; c += 1024) {
        short8 hv = ((const short8*)ehi)[c];
        short8 lv = ((const short8*)elo)[c];
        int byteoff = c * 16;
        int row     = byteoff >> 7;             // 128 B per code row
        int addr    = byteoff ^ ((row & 7) << 4);
        *(short8*)((char*)s_e[0] + addr) = hv;
        *(short8*)((char*)s_e[1] + addr) = lv;
    }
    if (tid < K) s_esq[tid] = g_esq[tid];
    __syncthreads();

    // B-fragments: lane slot (kg, j) holds x[query][h*32 + kg*8 + j], hi/lo split.
    // A-slots use the same (kg, j) -> dim map, so pairing is k-order independent.
    short8 xh[2][2], xl[2][2];
    #pragma unroll
    for (int qt = 0; qt < 2; ++qt) {
        #pragma unroll
        for (int h = 0; h < 2; ++h) {
            const float* p = x + (size_t)(qw + qt * 16 + qrow) * D + h * 32 + kg * 8;
            float4 v0 = *(const float4*)p;
            float4 v1 = *(const float4*)(p + 4);
            float vv[8] = {v0.x, v0.y, v0.z, v0.w, v1.x, v1.y, v1.z, v1.w};
            short8 th, tl;
            #pragma unroll
            for (int j = 0; j < 8; ++j) {
                unsigned short hb = f2bf(vv[j]);
                th[j] = (short)hb;
                tl[j] = (short)f2bf(vv[j] - bf2f(hb));
            }
            xh[qt][h] = th;
            xl[qt][h] = tl;
        }
    }

    float m1[2], m2[2];
    int   i1[2];
    #pragma unroll
    for (int qt = 0; qt < 2; ++qt) { m1[qt] = 3.4e38f; m2[qt] = 3.4e38f; i1[qt] = 0; }

    for (int t = 0; t < 32; ++t) {
        const int row  = t * 16 + qrow;         // A-operand code row
        const int swz  = (row & 7) << 4;
        const int off0 = row * 128 + kg * 16;
        short8 eh0 = *(const short8*)((const char*)s_e[0] + ((off0     ) ^ swz));
        short8 eh1 = *(const short8*)((const char*)s_e[0] + ((off0 + 64) ^ swz));
        short8 el0 = *(const short8*)((const char*)s_e[1] + ((off0     ) ^ swz));
        short8 el1 = *(const short8*)((const char*)s_e[1] + ((off0 + 64) ^ swz));
        f32x4 eq = *(const f32x4*)(s_esq + t * 16 + kg * 4);

        #pragma unroll
        for (int qt = 0; qt < 2; ++qt) {
            // two INDEPENDENT chains (2-deep + 4-deep); 4 chains in flight across qt
            f32x4 a0 = {0.f, 0.f, 0.f, 0.f};
            f32x4 a1 = {0.f, 0.f, 0.f, 0.f};
            a0 = __builtin_amdgcn_mfma_f32_16x16x32_bf16(eh0, xh[qt][0], a0, 0, 0, 0);
            a0 = __builtin_amdgcn_mfma_f32_16x16x32_bf16(eh1, xh[qt][1], a0, 0, 0, 0);
            a1 = __builtin_amdgcn_mfma_f32_16x16x32_bf16(eh0, xl[qt][0], a1, 0, 0, 0);
            a1 = __builtin_amdgcn_mfma_f32_16x16x32_bf16(eh1, xl[qt][1], a1, 0, 0, 0);
            a1 = __builtin_amdgcn_mfma_f32_16x16x32_bf16(el0, xh[qt][0], a1, 0, 0, 0);
            a1 = __builtin_amdgcn_mfma_f32_16x16x32_bf16(el1, xh[qt][1], a1, 0, 0, 0);
            #pragma unroll
            for (int r = 0; r < 4; ++r) {
                float dd = fmaf(-2.f, a0[r] + a1[r], eq[r]);  // d2 proxy
                int   kc = (t * 16 + r) | (kg * 4);           // disjoint bits
                bool  lt = dd < m1[qt];
                m2[qt] = lt ? m1[qt] : fminf(m2[qt], dd);
                m1[qt] = lt ? dd : m1[qt];
                i1[qt] = lt ? kc : i1[qt];
            }
        }
    }

    // combine (m1,i1,m2) across the 4 k-groups holding each query
    #pragma unroll
    for (int qt = 0; qt < 2; ++qt) {
        #pragma unroll
        for (int off = 16; off <= 32; off <<= 1) {
            float om1 = __shfl_xor(m1[qt], off, 64);
            float om2 = __shfl_xor(m2[qt], off, 64);
            int   oi  = __shfl_xor(i1[qt], off, 64);
            bool  lt  = om1 < m1[qt];
            float loser = lt ? m1[qt] : om1;
            m2[qt] = fminf(fminf(m2[qt], om2), loser);
            m1[qt] = lt ? om1 : m1[qt];
            i1[qt] = lt ? oi  : i1[qt];
        }
    }

    // exact fp32 rescan when top-2 gap <= THR >= 2*(bf16x3 bound): fp32 argmin
    // guaranteed; approx ties (gap 0) also land here -> first-index restored.
    #pragma unroll
    for (int qt = 0; qt < 2; ++qt) {
        bool flag = (m2[qt] - m1[qt]) <= THR;
        unsigned long long mask = __ballot(flag && (lane < 16));
        while (mask) {
            int ql = __ffsll(mask) - 1;
            mask &= mask - 1;
            int qf = qw + qt * 16 + ql;                 // wave-uniform
            const float* xq = x + (size_t)qf * D;
            float bb = 3.4e38f;
            int   bq = 0;
            #pragma unroll 1
            for (int c0 = 0; c0 < 8; ++c0) {
                int kc = lane * 8 + c0;
                const float4* ep = (const float4*)(cb + (size_t)kc * D);
                float a = 0.f;
                #pragma unroll
                for (int i = 0; i < 16; ++i) {
                    float4 e = ep[i];
                    a = fmaf(xq[4 * i + 0], e.x, a);
                    a = fmaf(xq[4 * i + 1], e.y, a);
                    a = fmaf(xq[4 * i + 2], e.z, a);
                    a = fmaf(xq[4 * i + 3], e.w, a);
                }
                float dd = fmaf(-2.f, a, s_esq[kc]);
                if (dd < bb) { bb = dd; bq = kc; }      // ascending kc: first index wins
            }
            #pragma unroll
            for (int off = 1; off < 64; off <<= 1) {    // min-reduce, first-index tie-break
                float ob = __shfl_xor(bb, off, 64);
                int   oq = __shfl_xor(bq, off, 64);
                if (ob < bb || (ob == bb && oq < bq)) { bb = ob; bq = oq; }
            }
            if (qrow == ql) i1[qt] = bq;
        }
    }

    // emit: out[q] = cb[i1]; lane (qrow,kg) writes 64 B of query qrow's row
    #pragma unroll
    for (int qt = 0; qt < 2; ++qt) {
        size_t q = (size_t)(qw + qt * 16 + qrow);
        const float4* src = (const float4*)(cb + (size_t)i1[qt] * D) + kg * 4;
        float4*       dst = (float4*)(out + q * D) + kg * 4;
        #pragma unroll
        for (int s = 0; s < 4; ++s) dst[s] = src[s];
    }
}

// ================= SAFE fallback: round-4 kernel verbatim (proven) =================
__global__ __launch_bounds__(512) void vq_mfma(
        const float* __restrict__ x, const float* __restrict__ cb,
        float* __restrict__ out) {

    __shared__ unsigned short s_e[2][K * D];
    __shared__ float s_esq[K];

    const int tid  = threadIdx.x;
    const int lane = tid & 63;
    const int qrow = lane & 15;
    const int kg   = lane >> 4;
    const int wv   = __builtin_amdgcn_readfirstlane(tid >> 6);
    const int qw   = blockIdx.x * 512 + wv * 64;

    const float4* cbv4 = (const float4*)cb;
    for (int c = tid; c < (K * D) / 4; c += 512) {
        float4 v = cbv4[c];
        float vv[4] = {v.x, v.y, v.z, v.w};
        short4v hi, lo;
        #pragma unroll
        for (int j = 0; j < 4; ++j) {
            unsigned short hb = f2bf(vv[j]);
            hi[j] = (short)hb;
            lo[j] = (short)f2bf(vv[j] - bf2f(hb));
        }
        int byteoff = c * 8;
        int row     = byteoff >> 7;
        int addr    = byteoff ^ ((row & 7) << 4);
        *(short4v*)((char*)s_e[0] + addr) = hi;
        *(short4v*)((char*)s_e[1] + addr) = lo;
    }
    {
        float s = 0.f;
        #pragma unroll
        for (int d = 0; d < D; ++d) {
            float v = cb[tid * D + d];
            s = fmaf(v, v, s);
        }
        s_esq[tid] = s;
    }
    __syncthreads();

    short8 xh[4][2], xl[4][2];
    #pragma unroll
    for (int qt = 0; qt < 4; ++qt) {
        #pragma unroll
        for (int h = 0; h < 2; ++h) {
            const float* p = x + (size_t)(qw + qt * 16 + qrow) * D + h * 32 + kg * 8;
            float4 v0 = *(const float4*)p;
            float4 v1 = *(const float4*)(p + 4);
            float vv[8] = {v0.x, v0.y, v0.z, v0.w, v1.x, v1.y, v1.z, v1.w};
            short8 th, tl;
            #pragma unroll
            for (int j = 0; j < 8; ++j) {
                unsigned short hb = f2bf(vv[j]);
                th[j] = (short)hb;
                tl[j] = (short)f2bf(vv[j] - bf2f(hb));
            }
            xh[qt][h] = th;
            xl[qt][h] = tl;
        }
    }

    float m1[4], m2[4];
    int   i1[4];
    #pragma unroll
    for (int qt = 0; qt < 4; ++qt) { m1[qt] = 3.4e38f; m2[qt] = 3.4e38f; i1[qt] = 0; }

    const f32x4 zacc = {0.f, 0.f, 0.f, 0.f};

    for (int t = 0; t < 32; ++t) {
        const int row  = t * 16 + qrow;
        const int swz  = (row & 7) << 4;
        const int off0 = row * 128 + kg * 16;
        short8 eh0 = *(const short8*)((const char*)s_e[0] + ((off0     ) ^ swz));
        short8 eh1 = *(const short8*)((const char*)s_e[0] + ((off0 + 64) ^ swz));
        short8 el0 = *(const short8*)((const char*)s_e[1] + ((off0     ) ^ swz));
        short8 el1 = *(const short8*)((const char*)s_e[1] + ((off0 + 64) ^ swz));
        f32x4 eq = *(const f32x4*)(s_esq + t * 16 + kg * 4);

        #pragma unroll
        for (int qt = 0; qt < 4; ++qt) {
            f32x4 acc;
            asm volatile(
                "s_nop 3\n\t"
                "v_mfma_f32_16x16x32_bf16 %0, %1, %5, %9\n\t"
                "v_mfma_f32_16x16x32_bf16 %0, %2, %6, %0\n\t"
                "v_mfma_f32_16x16x32_bf16 %0, %1, %7, %0\n\t"
                "v_mfma_f32_16x16x32_bf16 %0, %2, %8, %0\n\t"
                "v_mfma_f32_16x16x32_bf16 %0, %3, %5, %0\n\t"
                "v_mfma_f32_16x16x32_bf16 %0, %4, %6, %0\n\t"
                "s_nop 7\n\t"
                "s_nop 7"
                : "=&v"(acc)
                : "v"(eh0), "v"(eh1), "v"(el0), "v"(el1),
                  "v"(xh[qt][0]), "v"(xh[qt][1]), "v"(xl[qt][0]), "v"(xl[qt][1]),
                  "v"(zacc));
            #pragma unroll
            for (int r = 0; r < 4; ++r) {
                float dd = fmaf(-2.f, acc[r], eq[r]);
                int   kc = t * 16 + kg * 4 + r;
                bool  lt = dd < m1[qt];
                m2[qt] = lt ? m1[qt] : fminf(m2[qt], dd);
                m1[qt] = lt ? dd : m1[qt];
                i1[qt] = lt ? kc : i1[qt];
            }
        }
    }

    #pragma unroll
    for (int qt = 0; qt < 4; ++qt) {
        #pragma unroll
        for (int off = 16; off <= 32; off <<= 1) {
            float om1 = __shfl_xor(m1[qt], off, 64);
            float om2 = __shfl_xor(m2[qt], off, 64);
            int   oi  = __shfl_xor(i1[qt], off, 64);
            bool  lt  = om1 < m1[qt];
            float loser = lt ? m1[qt] : om1;
            m2[qt] = fminf(fminf(m2[qt], om2), loser);
            m1[qt] = lt ? om1 : m1[qt];
            i1[qt] = lt ? oi  : i1[qt];
        }
    }

    #pragma unroll
    for (int qt = 0; qt < 4; ++qt) {
        bool flag = (m2[qt] - m1[qt]) <= THR;
        unsigned long long mask = __ballot(flag && (lane < 16));
        while (mask) {
            int ql = __ffsll(mask) - 1;
            mask &= mask - 1;
            int qf = qw + qt * 16 + ql;
            const float* xq = x + (size_t)qf * D;
            float bb = 3.4e38f;
            int   bq = 0;
            #pragma unroll 1
            for (int c0 = 0; c0 < 8; ++c0) {
                int kc = lane * 8 + c0;
                const float4* ep = (const float4*)(cb + (size_t)kc * D);
                float a = 0.f;
                #pragma unroll
                for (int i = 0; i < 16; ++i) {
                    float4 e = ep[i];
                    a = fmaf(xq[4 * i + 0], e.x, a);
                    a = fmaf(xq[4 * i + 1], e.y, a);
                    a = fmaf(xq[4 * i + 2], e.z, a);
                    a = fmaf(xq[4 * i + 3], e.w, a);
                }
                float dd = fmaf(-2.f, a, s_esq[kc]);
                if (dd < bb) { bb = dd; bq = kc; }
            }
            #pragma unroll
            for (int off = 1; off < 64; off <<= 1) {
                float ob = __shfl_xor(bb, off, 64);
                int   oq = __shfl_xor(bq, off, 64);
                if (ob < bb || (ob == bb && oq < bq)) { bb = ob; bq = oq; }
            }
            if (qrow == ql) i1[qt] = bq;
        }
    }

    #pragma unroll
    for (int qt = 0; qt < 4; ++qt) {
        size_t q = (size_t)(qw + qt * 16 + qrow);
        const float4* src = (const float4*)(cb + (size_t)i1[qt] * D) + kg * 4;
        float4*       dst = (float4*)(out + q * D) + kg * 4;
        #pragma unroll
        for (int s = 0; s < 4; ++s) dst[s] = src[s];
    }
}

extern "C" void kernel_launch(void* const* d_in, const int* in_sizes, int n_in,
                              void* d_out, int out_size, void* d_ws, size_t ws_size,
                              hipStream_t stream) {
    const float* x   = (const float*)d_in[0];   // [8,16384,64]
    const float* cb  = (const float*)d_in[1];   // [512,64]
    float*       out = (float*)d_out;           // [8,16384,1,64]

    const size_t need = 2048 + (size_t)K * D * 2 * 2;   // esq + ehi + elo = 133120 B
    if (ws_size >= need) {
        float*          esq = (float*)d_ws;
        unsigned short* ehi = (unsigned short*)((char*)d_ws + 2048);
        unsigned short* elo = (unsigned short*)((char*)d_ws + 2048 + K * D * 2);
        prep_kernel<<<1, 512, 0, stream>>>(cb, esq, ehi, elo);
        vq_mfma3<<<QTOT / 512, 1024, 0, stream>>>(x, cb, esq, ehi, elo, out);
    } else {
        vq_mfma<<<QTOT / 512, 512, 0, stream>>>(x, cb, out);
    }
}